// Round 16
// baseline (522.020 us; speedup 1.0000x reference)
//
#include <hip/hip_runtime.h>
#include <hip/hip_bf16.h>
#include <stdint.h>

#define T_SEQ 4096
#define KVB 64
#define BM 128
#define BN 128
#define BK 64
#define SCL2 (0.08838834764831845f * 1.44269504088896340f)

typedef unsigned short u16;
typedef __attribute__((ext_vector_type(8))) short s16x8;
typedef __attribute__((ext_vector_type(4))) short s16x4;
typedef __attribute__((ext_vector_type(4))) float f32x4;

__device__ __forceinline__ u16 f2bf(float f) {
  union { float f; unsigned u; } a; a.f = f;
  unsigned r = a.u + 0x7fffu + ((a.u >> 16) & 1u);
  return (u16)(r >> 16);
}
__device__ __forceinline__ float bf2f(u16 b) {
  union { unsigned u; float f; } a; a.u = ((unsigned)b) << 16;
  return a.f;
}
__device__ __forceinline__ unsigned cvtpk(float lo, float hi) {
  unsigned r;
  asm volatile("v_cvt_pk_bf16_f32 %0, %1, %2" : "=v"(r) : "v"(lo), "v"(hi));
  return r;
}

__device__ __forceinline__ void gl_lds16(const void* g, void* l) {
  __builtin_amdgcn_global_load_lds((const __attribute__((address_space(1))) void*)g,
                                   (__attribute__((address_space(3))) void*)l, 16, 0, 0);
}

// ---------------- fused prep: hidden cvt + 4 weight transpose-cvts ----------------
__global__ __launch_bounds__(256) void k_prep(const float* __restrict__ hidden, u16* __restrict__ Xb,
                                              const float* __restrict__ Wq, const float* __restrict__ Wk,
                                              const float* __restrict__ Wv, const float* __restrict__ Wo,
                                              u16* __restrict__ Bqkv, u16* __restrict__ Wot) {
  __shared__ float tile[32][33];
  int bid = blockIdx.x;
  if (bid < 4096) {
    int i = (bid * 256 + threadIdx.x) * 8;
    const float4* p = (const float4*)(hidden + i);
    float4 a = p[0], b = p[1];
    s16x8 o;
    o[0] = (short)f2bf(a.x); o[1] = (short)f2bf(a.y); o[2] = (short)f2bf(a.z); o[3] = (short)f2bf(a.w);
    o[4] = (short)f2bf(b.x); o[5] = (short)f2bf(b.y); o[6] = (short)f2bf(b.z); o[7] = (short)f2bf(b.w);
    *(s16x8*)(Xb + i) = o;
    return;
  }
  const float* in;
  u16* out;
  int R, C, l;
  if (bid < 8192)       { in = Wq; out = Bqkv;              R = 2048; C = 2048; l = bid - 4096; }
  else if (bid < 9216)  { in = Wk; out = Bqkv + 2048 * 2048; R = 2048; C = 512;  l = bid - 8192; }
  else if (bid < 10240) { in = Wv; out = Bqkv + 2560 * 2048; R = 2048; C = 512;  l = bid - 9216; }
  else                  { in = Wo; out = Wot;               R = 2048; C = 2048; l = bid - 10240; }
  int nbx = C >> 5;
  int bx = l % nbx, by = l / nbx;
  int c0 = bx * 32, r0 = by * 32;
  int tx = threadIdx.x & 31, ty = threadIdx.x >> 5;
#pragma unroll
  for (int k = 0; k < 4; k++) tile[ty + 8 * k][tx] = in[(size_t)(r0 + ty + 8 * k) * C + c0 + tx];
  __syncthreads();
#pragma unroll
  for (int k = 0; k < 4; k++) out[(size_t)(c0 + ty + 8 * k) * R + r0 + tx] = f2bf(tile[tx][ty + 8 * k]);
}

// ---------------- GEMM: C[m][n] = sum_k A[m][k]*Bt[n][k]  (A,Bt bf16) ----------------
// XCD-bijective block swizzle (grid total % 8 == 0): each XCD gets contiguous m-rows -> A panels L2-held.
__global__ __launch_bounds__(256, 2) void k_gemm(const u16* __restrict__ A, const u16* __restrict__ Bt,
                                                 u16* __restrict__ Cq, u16* __restrict__ Ck, u16* __restrict__ Cvt,
                                                 float* __restrict__ Cf, int M, int N, int Kd, int mode) {
  __shared__ u16 SM[BM * BK + BN * BK];
  u16* As = SM;
  u16* Bs = SM + BM * BK;
  int tid = threadIdx.x, lane = tid & 63, w = tid >> 6;
  int g = lane >> 4, r16 = lane & 15;
  int lidb = blockIdx.y * gridDim.x + blockIdx.x;
  int per = (gridDim.x * gridDim.y) >> 3;
  int nid = (lidb & 7) * per + (lidb >> 3);
  int ty = nid / gridDim.x;
  int m0 = ty * BM, n0 = (nid - ty * gridDim.x) * BN;
  int wr = w >> 1, wc = w & 1;
  f32x4 acc[4][4] = {};

  for (int kt = 0; kt < Kd; kt += BK) {
#pragma unroll
    for (int i = 0; i < 4; i++) {
      int idx = i * 256 + tid;
      int row = idx >> 3, c = idx & 7;
      int cs = c ^ (row & 7);
      gl_lds16(A + (size_t)(m0 + row) * Kd + kt + cs * 8, As + (i * 256 + w * 64) * 8);
    }
#pragma unroll
    for (int i = 0; i < 4; i++) {
      int idx = i * 256 + tid;
      int row = idx >> 3, c = idx & 7;
      int cs = c ^ (row & 7);
      gl_lds16(Bt + (size_t)(n0 + row) * Kd + kt + cs * 8, Bs + (i * 256 + w * 64) * 8);
    }
    __syncthreads();
#pragma unroll
    for (int kk = 0; kk < 2; kk++) {
      s16x8 af[4], bfr[4];
#pragma unroll
      for (int mi = 0; mi < 4; mi++) {
        int row = wr * 64 + mi * 16 + r16;
        af[mi] = *(const s16x8*)(As + row * 64 + (((kk * 4 + g) ^ (row & 7)) * 8));
      }
#pragma unroll
      for (int ni = 0; ni < 4; ni++) {
        int row = wc * 64 + ni * 16 + r16;
        bfr[ni] = *(const s16x8*)(Bs + row * 64 + (((kk * 4 + g) ^ (row & 7)) * 8));
      }
#pragma unroll
      for (int mi = 0; mi < 4; mi++)
#pragma unroll
        for (int ni = 0; ni < 4; ni++)
          acc[mi][ni] = __builtin_amdgcn_mfma_f32_16x16x32_bf16(af[mi], bfr[ni], acc[mi][ni], 0, 0, 0);
    }
    __syncthreads();
  }

#pragma unroll
  for (int mi = 0; mi < 4; mi++) {
    int rowb = m0 + wr * 64 + mi * 16 + g * 4;
#pragma unroll
    for (int ni = 0; ni < 4; ni++) {
      int ncol0 = n0 + wc * 64 + ni * 16;
      int col = ncol0 + r16;
      if (mode == 0) {
        if (ncol0 < 2048) {
#pragma unroll
          for (int j = 0; j < 4; j++) Cq[(size_t)(rowb + j) * 2048 + col] = f2bf(acc[mi][ni][j]);
        } else if (ncol0 < 2560) {
#pragma unroll
          for (int j = 0; j < 4; j++) Ck[(size_t)(rowb + j) * 512 + (col - 2048)] = f2bf(acc[mi][ni][j]);
        } else {
          s16x4 pk;
#pragma unroll
          for (int j = 0; j < 4; j++) pk[j] = (short)f2bf(acc[mi][ni][j]);
          *(s16x4*)(Cvt + (size_t)(col - 2560) * T_SEQ + rowb) = pk;
        }
      } else {
#pragma unroll
        for (int j = 0; j < 4; j++) Cf[(size_t)(rowb + j) * N + col] = acc[mi][ni][j];
      }
    }
  }
}

// ---------------- RMSNorm + RoPE (+ fold attention scale into Q) ----------------
__global__ __launch_bounds__(256) void k_normrope(u16* __restrict__ Q, u16* __restrict__ Kc,
                                                  const float* __restrict__ sinT, const float* __restrict__ cosT,
                                                  const float* __restrict__ qsc, const float* __restrict__ ksc) {
  int t = blockIdx.x;
  int w = threadIdx.x >> 6, lane = threadIdx.x & 63;
  int unit = blockIdx.y * 4 + w;  // 0..15 Q heads, 16..19 K heads
  u16* base;
  const float* sc;
  float fold;
  if (unit < 16) { base = Q + (size_t)t * 2048 + unit * 128; sc = qsc; fold = SCL2; }
  else { base = Kc + (size_t)t * 512 + (unit - 16) * 128; sc = ksc; fold = 1.0f; }
  float x1 = bf2f(base[lane]), x2 = bf2f(base[lane + 64]);
  float ss = x1 * x1 + x2 * x2;
#pragma unroll
  for (int off = 32; off >= 1; off >>= 1) ss += __shfl_xor(ss, off);
  float rinv = rsqrtf(ss * (1.0f / 128.0f) + 1e-6f);
  float n1 = x1 * rinv * sc[lane], n2 = x2 * rinv * sc[lane + 64];
  float s = sinT[t * 64 + lane], c = cosT[t * 64 + lane];
  base[lane] = f2bf((n1 * c - n2 * s) * fold);
  base[lane + 64] = f2bf((n2 * c + n1 * s) * fold);
}

// ---------------- Flash attention (causal GQA) — 64 q-rows/wave, fixed-max softmax ----------------
// Q [T][2048] bf16 (pre-scaled by SCALE*log2e), Kc [T][512], Vt [512][T], O [T][2048]
// 512 blocks x 256 thr (4 waves = 2 qs x 2 ks); wave owns 64 q-rows (4 qc) x 32-key slice.
// Each kf/vf LDS read now feeds 4 MFMAs (was 2) -> LDS-read traffic per unit work x0.64.
// Fixed-max softmax (M=24 folded into MFMA C-init), l via ones-MFMA, single barrier/tile.
// LDS 69KB: K dbuf 2x16K [0,32K) | V dbuf 2x16K [32K,64K) | P 4x1280B [64K,69K). 2 blocks/CU.
__global__ __launch_bounds__(256, 2) void k_attn(const u16* __restrict__ Q, const u16* __restrict__ Kc,
                                                 const u16* __restrict__ Vt, u16* __restrict__ O) {
  __shared__ __align__(16) char SMc[70656];
  int tid = threadIdx.x, lane = tid & 63, w = tid >> 6;
  int g = lane >> 4, r16 = lane & 15;
  int qs = w >> 1, ks = w & 1;

  // bid -> (xcd, head, qb): blocks b and b+256 share xcd and head-parity; qb complementary.
  int bid = blockIdx.x;
  int xcd = bid & 7;
  int lid = bid >> 3;                 // 0..63 within XCD
  int h = xcd * 2 + (lid & 1);
  int i2 = lid >> 1;                  // 0..31
  int qb = (i2 < 16) ? i2 : 47 - i2;  // pair (lid, lid+32): qb + qb' = 31
  int gh = h >> 2;
  int q0 = qb * 128;
  int qwv = q0 + qs * 64;             // this wave's 64 q-rows
  int nt = 2 * qb + 2;

  s16x8 qf[4][4];
#pragma unroll
  for (int qc = 0; qc < 4; qc++)
#pragma unroll
    for (int dc = 0; dc < 4; dc++)
      qf[qc][dc] = *(const s16x8*)(Q + (size_t)(qwv + qc * 16 + r16) * 2048 + h * 128 + dc * 32 + g * 8);

  s16x8 onesA;
#pragma unroll
  for (int j = 0; j < 8; j++) onesA[j] = (short)0x3F80;  // bf16 1.0

  auto STAGE = [&](int bb, int tt) {
    int kv0 = tt * KVB;
    u16* Kb = (u16*)(SMc + bb * 16384);
    u16* Vb = (u16*)(SMc + 32768 + bb * 16384);
#pragma unroll
    for (int i = 0; i < 4; i++) {
      int idx = i * 256 + tid;
      int row = idx >> 4, cc = idx & 15;
      int cs = cc ^ (row & 7);
      gl_lds16(Kc + (size_t)(kv0 + row) * 512 + gh * 128 + cs * 8, Kb + (i * 256 + w * 64) * 8);
    }
#pragma unroll
    for (int i = 0; i < 4; i++) {
      int idx = i * 256 + tid;
      int row = idx >> 3, cc = idx & 7;
      int cs = cc ^ (row & 7);
      gl_lds16(Vt + (size_t)(gh * 128 + row) * T_SEQ + kv0 + cs * 8, Vb + (i * 256 + w * 64) * 8);
    }
  };

  f32x4 acc[4][8] = {};
  f32x4 acc_l[4] = {};  // l accumulator: mfma(ones, P) -> every reg = row-sum of P

  STAGE(0, 0);
  __syncthreads();

  const f32x4 mInit = {-24.0f, -24.0f, -24.0f, -24.0f};

  for (int t = 0; t < nt; ++t) {
    int kv0 = t * KVB;
    int bb = t & 1;
    STAGE(bb ^ 1, (t + 1 < nt) ? t + 1 : 0);  // prefetch next (wrap = dummy, unread)

    int kvw = kv0 + ks * 32;  // this wave's 32-key slice
    if (kvw <= qwv + 63) {    // wave-uniform causal skip (wave spans 64 q-rows)
      u16* Kb = (u16*)(SMc + bb * 16384);
      u16* Vb = (u16*)(SMc + 32768 + bb * 16384);
      char* Pwb = SMc + 65536 + w * 1280;  // 16 rows x 80B, one qc at a time

      // S - 24 = K @ Q^T + (-24): sv[qc][kc] lane holds key = kvw+kc*16+g*4+reg, q = qwv+qc*16+r16
      f32x4 sv[4][2];
#pragma unroll
      for (int qc = 0; qc < 4; qc++) { sv[qc][0] = mInit; sv[qc][1] = mInit; }
      s16x8 pfr[4];
      __builtin_amdgcn_s_setprio(1);
#pragma unroll
      for (int kc = 0; kc < 2; kc++) {
        int krow = ks * 32 + kc * 16 + r16;
#pragma unroll
        for (int dc = 0; dc < 4; dc++) {
          s16x8 kf = *(const s16x8*)((u16*)Kb + krow * 128 + (((dc * 4 + g) ^ (krow & 7)) * 8));
#pragma unroll
          for (int qc = 0; qc < 4; qc++)
            sv[qc][kc] = __builtin_amdgcn_mfma_f32_16x16x32_bf16(kf, qf[qc][dc], sv[qc][kc], 0, 0, 0);
        }
      }
      __builtin_amdgcn_s_setprio(0);

#pragma unroll
      for (int qc = 0; qc < 4; qc++) {
        int qg = qwv + qc * 16 + r16;
        bool needmask = (kvw + 31) > (qwv + qc * 16);
        if (needmask) {
#pragma unroll
          for (int kc = 0; kc < 2; kc++)
#pragma unroll
            for (int j2 = 0; j2 < 4; j2++)
              if (kvw + kc * 16 + g * 4 + j2 > qg) sv[qc][kc][j2] = -3.0e38f;
        }
#pragma unroll
        for (int kc = 0; kc < 2; kc++) {
          float p0 = exp2f(sv[qc][kc][0]);
          float p1 = exp2f(sv[qc][kc][1]);
          float p2 = exp2f(sv[qc][kc][2]);
          float p3 = exp2f(sv[qc][kc][3]);
          uint2 pk;
          pk.x = cvtpk(p0, p1);
          pk.y = cvtpk(p2, p3);
          *(uint2*)(Pwb + r16 * 80 + (kc * 2 + (g >> 1)) * 16 + (g & 1) * 8) = pk;
        }
        // pf read: keys g*8..g*8+7 for q=r16
        pfr[qc] = *(const s16x8*)(Pwb + r16 * 80 + g * 16);
      }

      // PV: acc[qc][df] lane holds dim = df*16+g*4+reg, q = r16 (keys = this wave's slice)
      __builtin_amdgcn_s_setprio(1);
#pragma unroll
      for (int df = 0; df < 8; df++) {
        int vrow = df * 16 + r16;
        s16x8 vf = *(const s16x8*)((u16*)Vb + vrow * 64 + (((ks * 4 + g) ^ (vrow & 7)) * 8));
#pragma unroll
        for (int qc = 0; qc < 4; qc++)
          acc[qc][df] = __builtin_amdgcn_mfma_f32_16x16x32_bf16(vf, pfr[qc], acc[qc][df], 0, 0, 0);
      }
      // l += ones^T @ P : every acc_l reg = sum_k P[k][q]
#pragma unroll
      for (int qc = 0; qc < 4; qc++)
        acc_l[qc] = __builtin_amdgcn_mfma_f32_16x16x32_bf16(onesA, pfr[qc], acc_l[qc], 0, 0, 0);
      __builtin_amdgcn_s_setprio(0);
    }
    __syncthreads();
  }

  // ---- pair-merge (ks=0 + ks=1 key-slices): fixed max -> plain sums of O and l ----
  float* ml = (float*)(SMc + 65536);  // [4 waves][4 qc][16 r16] = 1KB (P region, dead)
#pragma unroll
  for (int qc = 0; qc < 4; qc++)
    if (g == 0) ml[(w * 4 + qc) * 16 + r16] = acc_l[qc][0];
  __syncthreads();
  int pw = w ^ 1;  // partner wave (other ks, same qs)
  float scale[4];
#pragma unroll
  for (int qc = 0; qc < 4; qc++) {
    float pl = ml[(pw * 4 + qc) * 16 + r16];
    scale[qc] = 1.0f / (acc_l[qc][0] + pl);
  }
  if (ks == 0) {  // write scaled f32 partials: [qs][64 rows][128 dims] swizzled, [0,64K)
#pragma unroll
    for (int qc = 0; qc < 4; qc++)
#pragma unroll
      for (int df = 0; df < 8; df++) {
        f32x4 v = acc[qc][df] * scale[qc];
        *(f32x4*)(SMc + qs * 32768 + (qc * 16 + r16) * 512 + (((df * 4 + g) ^ (r16 & 7)) * 16)) = v;
      }
  }
  __syncthreads();
  if (ks == 1) {  // merge + store
#pragma unroll
    for (int qc = 0; qc < 4; qc++)
#pragma unroll
      for (int df = 0; df < 8; df++) {
        f32x4 p = *(const f32x4*)(SMc + qs * 32768 + (qc * 16 + r16) * 512 + (((df * 4 + g) ^ (r16 & 7)) * 16));
        f32x4 o = p + acc[qc][df] * scale[qc];
        uint2 pk;
        pk.x = cvtpk(o[0], o[1]);
        pk.y = cvtpk(o[2], o[3]);
        *(uint2*)(O + (size_t)(qwv + qc * 16 + r16) * 2048 + h * 128 + df * 16 + g * 4) = pk;
      }
  }
}

extern "C" void kernel_launch(void* const* d_in, const int* in_sizes, int n_in,
                              void* d_out, int out_size, void* d_ws, size_t ws_size,
                              hipStream_t stream) {
  const float* hidden = (const float*)d_in[0];
  const float* sinT = (const float*)d_in[1];
  const float* cosT = (const float*)d_in[2];
  // d_in[3] = mask (bool tril) — causal hardcoded
  const float* Wq = (const float*)d_in[4];
  const float* Wk = (const float*)d_in[5];
  const float* Wv = (const float*)d_in[6];
  const float* Wo = (const float*)d_in[7];
  const float* qsc = (const float*)d_in[8];
  const float* ksc = (const float*)d_in[9];
  float* out = (float*)d_out;

  char* ws = (char*)d_ws;
  u16* Xb   = (u16*)(ws + 0);          // [4096][2048]      16.78 MB
  u16* Bqkv = (u16*)(ws + 16777216);   // [3072][2048]      12.58 MB
  u16* Wot  = (u16*)(ws + 29360128);   // [2048][2048]       8.39 MB
  u16* Qraw = (u16*)(ws + 37748736);   // [4096][2048]      16.78 MB
  u16* Kraw = (u16*)(ws + 54525952);   // [4096][512]        4.19 MB
  u16* Vt   = (u16*)(ws + 58720256);   // [512][4096]        4.19 MB
  u16* Oat  = (u16*)(ws + 62914560);   // [4096][2048]      16.78 MB  (end 79.7 MB)

  k_prep<<<dim3(14336), dim3(256), 0, stream>>>(hidden, Xb, Wq, Wk, Wv, Wo, Bqkv, Wot);
  k_gemm<<<dim3(24, 32), dim3(256), 0, stream>>>(Xb, Bqkv, Qraw, Kraw, Vt, (float*)nullptr,
                                                 4096, 3072, 2048, 0);
  k_normrope<<<dim3(4096, 5), dim3(256), 0, stream>>>(Qraw, Kraw, sinT, cosT, qsc, ksc);
  k_attn<<<dim3(512), dim3(256), 0, stream>>>(Qraw, Kraw, Vt, Oat);
  k_gemm<<<dim3(16, 32), dim3(256), 0, stream>>>(Oat, Wot, (u16*)nullptr, (u16*)nullptr, (u16*)nullptr,
                                                 out, 4096, 2048, 2048, 1);
}

// Round 17
// 223.017 us; speedup vs baseline: 2.3407x; 2.3407x over previous
//
#include <hip/hip_runtime.h>
#include <hip/hip_bf16.h>
#include <stdint.h>

#define T_SEQ 4096
#define KVB 64
#define BM 128
#define BN 128
#define BK 64
#define SCL2 (0.08838834764831845f * 1.44269504088896340f)

typedef unsigned short u16;
typedef __attribute__((ext_vector_type(8))) short s16x8;
typedef __attribute__((ext_vector_type(4))) short s16x4;
typedef __attribute__((ext_vector_type(4))) float f32x4;

__device__ __forceinline__ u16 f2bf(float f) {
  union { float f; unsigned u; } a; a.f = f;
  unsigned r = a.u + 0x7fffu + ((a.u >> 16) & 1u);
  return (u16)(r >> 16);
}
__device__ __forceinline__ float bf2f(u16 b) {
  union { unsigned u; float f; } a; a.u = ((unsigned)b) << 16;
  return a.f;
}
__device__ __forceinline__ unsigned cvtpk(float lo, float hi) {
  unsigned r;
  asm volatile("v_cvt_pk_bf16_f32 %0, %1, %2" : "=v"(r) : "v"(lo), "v"(hi));
  return r;
}

__device__ __forceinline__ void gl_lds16(const void* g, void* l) {
  __builtin_amdgcn_global_load_lds((const __attribute__((address_space(1))) void*)g,
                                   (__attribute__((address_space(3))) void*)l, 16, 0, 0);
}

// ---------------- fused prep: hidden cvt + 4 weight transpose-cvts ----------------
__global__ __launch_bounds__(256) void k_prep(const float* __restrict__ hidden, u16* __restrict__ Xb,
                                              const float* __restrict__ Wq, const float* __restrict__ Wk,
                                              const float* __restrict__ Wv, const float* __restrict__ Wo,
                                              u16* __restrict__ Bqkv, u16* __restrict__ Wot) {
  __shared__ float tile[32][33];
  int bid = blockIdx.x;
  if (bid < 4096) {
    int i = (bid * 256 + threadIdx.x) * 8;
    const float4* p = (const float4*)(hidden + i);
    float4 a = p[0], b = p[1];
    s16x8 o;
    o[0] = (short)f2bf(a.x); o[1] = (short)f2bf(a.y); o[2] = (short)f2bf(a.z); o[3] = (short)f2bf(a.w);
    o[4] = (short)f2bf(b.x); o[5] = (short)f2bf(b.y); o[6] = (short)f2bf(b.z); o[7] = (short)f2bf(b.w);
    *(s16x8*)(Xb + i) = o;
    return;
  }
  const float* in;
  u16* out;
  int R, C, l;
  if (bid < 8192)       { in = Wq; out = Bqkv;              R = 2048; C = 2048; l = bid - 4096; }
  else if (bid < 9216)  { in = Wk; out = Bqkv + 2048 * 2048; R = 2048; C = 512;  l = bid - 8192; }
  else if (bid < 10240) { in = Wv; out = Bqkv + 2560 * 2048; R = 2048; C = 512;  l = bid - 9216; }
  else                  { in = Wo; out = Wot;               R = 2048; C = 2048; l = bid - 10240; }
  int nbx = C >> 5;
  int bx = l % nbx, by = l / nbx;
  int c0 = bx * 32, r0 = by * 32;
  int tx = threadIdx.x & 31, ty = threadIdx.x >> 5;
#pragma unroll
  for (int k = 0; k < 4; k++) tile[ty + 8 * k][tx] = in[(size_t)(r0 + ty + 8 * k) * C + c0 + tx];
  __syncthreads();
#pragma unroll
  for (int k = 0; k < 4; k++) out[(size_t)(c0 + ty + 8 * k) * R + r0 + tx] = f2bf(tile[tx][ty + 8 * k]);
}

// ---------------- GEMM: C[m][n] = sum_k A[m][k]*Bt[n][k]  (A,Bt bf16) ----------------
// XCD-bijective block swizzle (grid total % 8 == 0): each XCD gets contiguous m-rows -> A panels L2-held.
__global__ __launch_bounds__(256, 2) void k_gemm(const u16* __restrict__ A, const u16* __restrict__ Bt,
                                                 u16* __restrict__ Cq, u16* __restrict__ Ck, u16* __restrict__ Cvt,
                                                 float* __restrict__ Cf, int M, int N, int Kd, int mode) {
  __shared__ u16 SM[BM * BK + BN * BK];
  u16* As = SM;
  u16* Bs = SM + BM * BK;
  int tid = threadIdx.x, lane = tid & 63, w = tid >> 6;
  int g = lane >> 4, r16 = lane & 15;
  int lidb = blockIdx.y * gridDim.x + blockIdx.x;
  int per = (gridDim.x * gridDim.y) >> 3;
  int nid = (lidb & 7) * per + (lidb >> 3);
  int ty = nid / gridDim.x;
  int m0 = ty * BM, n0 = (nid - ty * gridDim.x) * BN;
  int wr = w >> 1, wc = w & 1;
  f32x4 acc[4][4] = {};

  for (int kt = 0; kt < Kd; kt += BK) {
#pragma unroll
    for (int i = 0; i < 4; i++) {
      int idx = i * 256 + tid;
      int row = idx >> 3, c = idx & 7;
      int cs = c ^ (row & 7);
      gl_lds16(A + (size_t)(m0 + row) * Kd + kt + cs * 8, As + (i * 256 + w * 64) * 8);
    }
#pragma unroll
    for (int i = 0; i < 4; i++) {
      int idx = i * 256 + tid;
      int row = idx >> 3, c = idx & 7;
      int cs = c ^ (row & 7);
      gl_lds16(Bt + (size_t)(n0 + row) * Kd + kt + cs * 8, Bs + (i * 256 + w * 64) * 8);
    }
    __syncthreads();
#pragma unroll
    for (int kk = 0; kk < 2; kk++) {
      s16x8 af[4], bfr[4];
#pragma unroll
      for (int mi = 0; mi < 4; mi++) {
        int row = wr * 64 + mi * 16 + r16;
        af[mi] = *(const s16x8*)(As + row * 64 + (((kk * 4 + g) ^ (row & 7)) * 8));
      }
#pragma unroll
      for (int ni = 0; ni < 4; ni++) {
        int row = wc * 64 + ni * 16 + r16;
        bfr[ni] = *(const s16x8*)(Bs + row * 64 + (((kk * 4 + g) ^ (row & 7)) * 8));
      }
#pragma unroll
      for (int mi = 0; mi < 4; mi++)
#pragma unroll
        for (int ni = 0; ni < 4; ni++)
          acc[mi][ni] = __builtin_amdgcn_mfma_f32_16x16x32_bf16(af[mi], bfr[ni], acc[mi][ni], 0, 0, 0);
    }
    __syncthreads();
  }

#pragma unroll
  for (int mi = 0; mi < 4; mi++) {
    int rowb = m0 + wr * 64 + mi * 16 + g * 4;
#pragma unroll
    for (int ni = 0; ni < 4; ni++) {
      int ncol0 = n0 + wc * 64 + ni * 16;
      int col = ncol0 + r16;
      if (mode == 0) {
        if (ncol0 < 2048) {
#pragma unroll
          for (int j = 0; j < 4; j++) Cq[(size_t)(rowb + j) * 2048 + col] = f2bf(acc[mi][ni][j]);
        } else if (ncol0 < 2560) {
#pragma unroll
          for (int j = 0; j < 4; j++) Ck[(size_t)(rowb + j) * 512 + (col - 2048)] = f2bf(acc[mi][ni][j]);
        } else {
          s16x4 pk;
#pragma unroll
          for (int j = 0; j < 4; j++) pk[j] = (short)f2bf(acc[mi][ni][j]);
          *(s16x4*)(Cvt + (size_t)(col - 2560) * T_SEQ + rowb) = pk;
        }
      } else {
#pragma unroll
        for (int j = 0; j < 4; j++) Cf[(size_t)(rowb + j) * N + col] = acc[mi][ni][j];
      }
    }
  }
}

// ---------------- RMSNorm + RoPE for K only (Q fused into attn prologue) ----------------
__global__ __launch_bounds__(256) void k_normK(u16* __restrict__ Kc,
                                               const float* __restrict__ sinT, const float* __restrict__ cosT,
                                               const float* __restrict__ ksc) {
  int t = blockIdx.x;
  int w = threadIdx.x >> 6, lane = threadIdx.x & 63;  // wave w = K head w
  u16* base = Kc + (size_t)t * 512 + w * 128;
  float x1 = bf2f(base[lane]), x2 = bf2f(base[lane + 64]);
  float ss = x1 * x1 + x2 * x2;
#pragma unroll
  for (int off = 32; off >= 1; off >>= 1) ss += __shfl_xor(ss, off);
  float rinv = rsqrtf(ss * (1.0f / 128.0f) + 1e-6f);
  float n1 = x1 * rinv * ksc[lane], n2 = x2 * rinv * ksc[lane + 64];
  float s = sinT[t * 64 + lane], c = cosT[t * 64 + lane];
  base[lane] = f2bf(n1 * c - n2 * s);
  base[lane + 64] = f2bf(n2 * c + n1 * s);
}

// ---------------- Flash attention (causal GQA) — fixed-max softmax, fused Q norm+RoPE ----------------
// Qraw [T][2048] bf16 (raw gemm output), Kc [T][512] (normed+roped), Vt [512][T], O [T][2048]
// Q RMS-norm + RoPE + SCALE*log2e fold done IN-PROLOGUE: each Q row lives on 4 lanes (g, fixed r16)
// -> RMS sum = 2 shfl_xor; RoPE partner dim (d, d+64) = (dc, dc+2) on the SAME lane -> lane-local.
// Fixed softmax max M=24 folded into QK MFMA C-init; l via ones-MFMA; single barrier/tile.
// 512 blocks x 512 thr (8 waves = 4 qs x 2 ks), QBLK=128. LDS 74KB: K dbuf | V dbuf | P 8x1280B.
__global__ __launch_bounds__(512, 2) void k_attn(const u16* __restrict__ Q, const u16* __restrict__ Kc,
                                                 const u16* __restrict__ Vt, u16* __restrict__ O,
                                                 const float* __restrict__ sinT, const float* __restrict__ cosT,
                                                 const float* __restrict__ qsc) {
  __shared__ __align__(16) char SMc[75776];
  int tid = threadIdx.x, lane = tid & 63, w = tid >> 6;
  int g = lane >> 4, r16 = lane & 15;
  int qs = w >> 1, ks = w & 1;

  // bid -> (xcd, head, qb): blocks b and b+256 share xcd and head-parity; qb complementary.
  int bid = blockIdx.x;
  int xcd = bid & 7;
  int lid = bid >> 3;                 // 0..63 within XCD
  int h = xcd * 2 + (lid & 1);
  int i2 = lid >> 1;                  // 0..31
  int qb = (i2 < 16) ? i2 : 47 - i2;  // pair (lid, lid+32): qb + qb' = 31
  int gh = h >> 2;
  int q0 = qb * 128;
  int qwv = q0 + qs * 32;
  int nt = 2 * qb + 2;

  s16x8 qf[2][4];
#pragma unroll
  for (int qc = 0; qc < 2; qc++)
#pragma unroll
    for (int dc = 0; dc < 4; dc++)
      qf[qc][dc] = *(const s16x8*)(Q + (size_t)(qwv + qc * 16 + r16) * 2048 + h * 128 + dc * 32 + g * 8);

  // ---- fused Q RMS-norm + RoPE + SCL2 fold (once per block, lane-local rotation) ----
#pragma unroll
  for (int qc = 0; qc < 2; qc++) {
    float v[4][8];
    float ss = 0.0f;
#pragma unroll
    for (int dc = 0; dc < 4; dc++)
#pragma unroll
      for (int e = 0; e < 8; e++) {
        float x = bf2f((u16)qf[qc][dc][e]);
        v[dc][e] = x;
        ss += x * x;
      }
    ss += __shfl_xor(ss, 16);
    ss += __shfl_xor(ss, 32);
    float rinv = rsqrtf(ss * (1.0f / 128.0f) + 1e-6f) * SCL2;
    int t = qwv + qc * 16 + r16;
    const float* cb = cosT + t * 64 + g * 8;
    const float* sb = sinT + t * 64 + g * 8;
#pragma unroll
    for (int dc = 0; dc < 2; dc++)
#pragma unroll
      for (int e = 0; e < 8; e++) {
        int d1 = dc * 32 + g * 8 + e;
        float cc = cb[dc * 32 + e];
        float sn = sb[dc * 32 + e];
        float n1 = v[dc][e] * rinv * qsc[d1];
        float n2 = v[dc + 2][e] * rinv * qsc[d1 + 64];
        qf[qc][dc][e] = (short)f2bf(n1 * cc - n2 * sn);
        qf[qc][dc + 2][e] = (short)f2bf(n2 * cc + n1 * sn);
      }
  }

  s16x8 onesA;
#pragma unroll
  for (int j = 0; j < 8; j++) onesA[j] = (short)0x3F80;  // bf16 1.0

  auto STAGE = [&](int bb, int tt) {
    int kv0 = tt * KVB;
    u16* Kb = (u16*)(SMc + bb * 16384);
    u16* Vb = (u16*)(SMc + 32768 + bb * 16384);
#pragma unroll
    for (int i = 0; i < 2; i++) {
      int idx = i * 512 + tid;
      int row = idx >> 4, cc = idx & 15;
      int cs = cc ^ (row & 7);
      gl_lds16(Kc + (size_t)(kv0 + row) * 512 + gh * 128 + cs * 8, Kb + (i * 512 + w * 64) * 8);
    }
#pragma unroll
    for (int i = 0; i < 2; i++) {
      int idx = i * 512 + tid;
      int row = idx >> 3, cc = idx & 7;
      int cs = cc ^ (row & 7);
      gl_lds16(Vt + (size_t)(gh * 128 + row) * T_SEQ + kv0 + cs * 8, Vb + (i * 512 + w * 64) * 8);
    }
  };

  f32x4 acc[2][8] = {};
  f32x4 acc_l[2] = {};  // l accumulator: mfma(ones, P) -> every reg = row-sum of P

  STAGE(0, 0);
  __syncthreads();

  const f32x4 mInit = {-24.0f, -24.0f, -24.0f, -24.0f};

  for (int t = 0; t < nt; ++t) {
    int kv0 = t * KVB;
    int bb = t & 1;
    STAGE(bb ^ 1, (t + 1 < nt) ? t + 1 : 0);  // prefetch next (wrap = dummy, unread)

    int kvw = kv0 + ks * 32;  // this wave's 32-key slice
    if (kvw <= qwv + 31) {    // wave-uniform causal skip
      u16* Kb = (u16*)(SMc + bb * 16384);
      u16* Vb = (u16*)(SMc + 32768 + bb * 16384);
      char* Pwb = SMc + 65536 + w * 1280;  // 16 rows x 80B, one qc at a time

      // S - 24 = K @ Q^T + (-24) : C-init folds the fixed softmax max.
      // sv[qc][kc] lane holds key = kvw+kc*16+g*4+reg, q = qwv+qc*16+r16
      f32x4 sv[2][2] = {mInit, mInit, mInit, mInit};
      s16x8 pfr[2];
      __builtin_amdgcn_s_setprio(1);
#pragma unroll
      for (int kc = 0; kc < 2; kc++) {
        int krow = ks * 32 + kc * 16 + r16;
#pragma unroll
        for (int dc = 0; dc < 4; dc++) {
          s16x8 kf = *(const s16x8*)((u16*)Kb + krow * 128 + (((dc * 4 + g) ^ (krow & 7)) * 8));
          sv[0][kc] = __builtin_amdgcn_mfma_f32_16x16x32_bf16(kf, qf[0][dc], sv[0][kc], 0, 0, 0);
          sv[1][kc] = __builtin_amdgcn_mfma_f32_16x16x32_bf16(kf, qf[1][dc], sv[1][kc], 0, 0, 0);
        }
      }
      __builtin_amdgcn_s_setprio(0);

#pragma unroll
      for (int qc = 0; qc < 2; qc++) {
        int qg = qwv + qc * 16 + r16;
        bool needmask = (kvw + 31) > (qwv + qc * 16);
        if (needmask) {
#pragma unroll
          for (int kc = 0; kc < 2; kc++)
#pragma unroll
            for (int j2 = 0; j2 < 4; j2++)
              if (kvw + kc * 16 + g * 4 + j2 > qg) sv[qc][kc][j2] = -3.0e38f;
        }
#pragma unroll
        for (int kc = 0; kc < 2; kc++) {
          float p0 = exp2f(sv[qc][kc][0]);
          float p1 = exp2f(sv[qc][kc][1]);
          float p2 = exp2f(sv[qc][kc][2]);
          float p3 = exp2f(sv[qc][kc][3]);
          uint2 pk;
          pk.x = cvtpk(p0, p1);
          pk.y = cvtpk(p2, p3);
          *(uint2*)(Pwb + r16 * 80 + (kc * 2 + (g >> 1)) * 16 + (g & 1) * 8) = pk;
        }
        // pf read: keys g*8..g*8+7 for q=r16
        pfr[qc] = *(const s16x8*)(Pwb + r16 * 80 + g * 16);
      }

      // PV: acc[qc][df] lane holds dim = df*16+g*4+reg, q = r16 (keys = this wave's slice)
      __builtin_amdgcn_s_setprio(1);
#pragma unroll
      for (int df = 0; df < 8; df++) {
        int vrow = df * 16 + r16;
        s16x8 vf = *(const s16x8*)((u16*)Vb + vrow * 64 + (((ks * 4 + g) ^ (vrow & 7)) * 8));
        acc[0][df] = __builtin_amdgcn_mfma_f32_16x16x32_bf16(vf, pfr[0], acc[0][df], 0, 0, 0);
        acc[1][df] = __builtin_amdgcn_mfma_f32_16x16x32_bf16(vf, pfr[1], acc[1][df], 0, 0, 0);
      }
      // l += ones^T @ P : every acc_l reg = sum_k P[k][q]
      acc_l[0] = __builtin_amdgcn_mfma_f32_16x16x32_bf16(onesA, pfr[0], acc_l[0], 0, 0, 0);
      acc_l[1] = __builtin_amdgcn_mfma_f32_16x16x32_bf16(onesA, pfr[1], acc_l[1], 0, 0, 0);
      __builtin_amdgcn_s_setprio(0);
    }
    __syncthreads();
  }

  float lrun[2] = {acc_l[0][0], acc_l[1][0]};

  // ---- pair-merge (ks=0 + ks=1 key-slices): fixed max -> plain sums of O and l ----
  float* ml = (float*)(SMc + 65536);  // [8 waves][2 qc][16 r16] (P region, dead)
#pragma unroll
  for (int qc = 0; qc < 2; qc++)
    if (g == 0) ml[(w * 2 + qc) * 16 + r16] = lrun[qc];
  __syncthreads();
  int pw = w ^ 1;  // partner wave (other ks, same qs)
  float scale[2];
#pragma unroll
  for (int qc = 0; qc < 2; qc++) {
    float pl = ml[(pw * 2 + qc) * 16 + r16];
    scale[qc] = 1.0f / (lrun[qc] + pl);
  }
  if (ks == 0) {  // write scaled f32 partials: [qs][32 rows][128 dims] swizzled, [0,64K)
#pragma unroll
    for (int qc = 0; qc < 2; qc++)
#pragma unroll
      for (int df = 0; df < 8; df++) {
        f32x4 v = acc[qc][df] * scale[qc];
        *(f32x4*)(SMc + qs * 16384 + (qc * 16 + r16) * 512 + (((df * 4 + g) ^ (r16 & 7)) * 16)) = v;
      }
  }
  __syncthreads();
  if (ks == 1) {  // merge + store
#pragma unroll
    for (int qc = 0; qc < 2; qc++)
#pragma unroll
      for (int df = 0; df < 8; df++) {
        f32x4 p = *(const f32x4*)(SMc + qs * 16384 + (qc * 16 + r16) * 512 + (((df * 4 + g) ^ (r16 & 7)) * 16));
        f32x4 o = p + acc[qc][df] * scale[qc];
        uint2 pk;
        pk.x = cvtpk(o[0], o[1]);
        pk.y = cvtpk(o[2], o[3]);
        *(uint2*)(O + (size_t)(q0 + qs * 32 + qc * 16 + r16) * 2048 + h * 128 + df * 16 + g * 4) = pk;
      }
  }
}

extern "C" void kernel_launch(void* const* d_in, const int* in_sizes, int n_in,
                              void* d_out, int out_size, void* d_ws, size_t ws_size,
                              hipStream_t stream) {
  const float* hidden = (const float*)d_in[0];
  const float* sinT = (const float*)d_in[1];
  const float* cosT = (const float*)d_in[2];
  // d_in[3] = mask (bool tril) — causal hardcoded
  const float* Wq = (const float*)d_in[4];
  const float* Wk = (const float*)d_in[5];
  const float* Wv = (const float*)d_in[6];
  const float* Wo = (const float*)d_in[7];
  const float* qsc = (const float*)d_in[8];
  const float* ksc = (const float*)d_in[9];
  float* out = (float*)d_out;

  char* ws = (char*)d_ws;
  u16* Xb   = (u16*)(ws + 0);          // [4096][2048]      16.78 MB
  u16* Bqkv = (u16*)(ws + 16777216);   // [3072][2048]      12.58 MB
  u16* Wot  = (u16*)(ws + 29360128);   // [2048][2048]       8.39 MB
  u16* Qraw = (u16*)(ws + 37748736);   // [4096][2048]      16.78 MB
  u16* Kraw = (u16*)(ws + 54525952);   // [4096][512]        4.19 MB
  u16* Vt   = (u16*)(ws + 58720256);   // [512][4096]        4.19 MB
  u16* Oat  = (u16*)(ws + 62914560);   // [4096][2048]      16.78 MB  (end 79.7 MB)

  k_prep<<<dim3(14336), dim3(256), 0, stream>>>(hidden, Xb, Wq, Wk, Wv, Wo, Bqkv, Wot);
  k_gemm<<<dim3(24, 32), dim3(256), 0, stream>>>(Xb, Bqkv, Qraw, Kraw, Vt, (float*)nullptr,
                                                 4096, 3072, 2048, 0);
  k_normK<<<dim3(4096), dim3(256), 0, stream>>>(Kraw, sinT, cosT, ksc);
  k_attn<<<dim3(512), dim3(512), 0, stream>>>(Qraw, Kraw, Vt, Oat, sinT, cosT, qsc);
  k_gemm<<<dim3(16, 32), dim3(256), 0, stream>>>(Oat, Wot, (u16*)nullptr, (u16*)nullptr, (u16*)nullptr,
                                                 out, 4096, 2048, 2048, 1);
}